// Round 11
// baseline (881.993 us; speedup 1.0000x reference)
//
#include <hip/hip_runtime.h>
#include <hip/hip_bf16.h>
#include <math.h>

// ---------------------------------------------------------------------------
// GraphSAGE 3-layer + classifier + log_softmax.  Round 10 (resubmit after
// infra timeout).
//  - transform v4: thread owns feature f, computes BOTH P[f],Q[f].
//    Weight columns in 128 VGPRs (float2 wv[64], compile-time indices,
//    launch_bounds(256,2) -> 256-VGPR cap so they STAY resident; round-8
//    cap=128 remat'd, round-9 LDS copy got hoisted to 204 VGPR + 48KB LDS).
//    LDS holds only the 128-row x-tile (32 KB).  Row-quad loop unroll 1.
//  - CSR packed-pair bucket sort + bf16-P gather unchanged.
// ---------------------------------------------------------------------------

#define BSHIFT 8
#define BUCKET 256
#define MAXB 512
#define SCAT_EDGES 8192
#define TROWS 128

__global__ __launch_bounds__(256) void hist_kernel(const int* __restrict__ dst,
                                                   int* __restrict__ ghist,
                                                   int E, int nbuck) {
    __shared__ int lh[MAXB];
    int t = threadIdx.x;
    lh[t] = 0; lh[t + 256] = 0;
    __syncthreads();
    int start = blockIdx.x * SCAT_EDGES;
    int end = min(E, start + SCAT_EDGES);
    for (int e = start + t; e < end; e += 256)
        atomicAdd(&lh[dst[e] >> BSHIFT], 1);
    __syncthreads();
    for (int b = t; b < nbuck; b += 256)
        if (lh[b]) atomicAdd(&ghist[b], lh[b]);
}

__global__ __launch_bounds__(512) void scanb_kernel(const int* __restrict__ ghist,
                                                    int* __restrict__ bbase,
                                                    int* __restrict__ gcur,
                                                    int nbuck, int E) {
    __shared__ int s[MAXB];
    int t = threadIdx.x;
    int v = (t < nbuck) ? ghist[t] : 0;
    s[t] = v;
    __syncthreads();
    for (int off = 1; off < MAXB; off <<= 1) {
        int u = (t >= off) ? s[t - off] : 0;
        __syncthreads();
        s[t] += u;
        __syncthreads();
    }
    int excl = s[t] - v;
    if (t < nbuck) { bbase[t] = excl; gcur[t] = excl; }
    if (t == 0) bbase[nbuck] = E;
}

__global__ __launch_bounds__(256) void scatter_kernel(const int* __restrict__ src,
                                                      const int* __restrict__ dst,
                                                      int* __restrict__ gcur,
                                                      unsigned int* __restrict__ pairs,
                                                      int E, int nbuck) {
    __shared__ int lh[MAXB];
    __shared__ int lbase[MAXB];
    __shared__ int lcur[MAXB];
    int t = threadIdx.x;
    lh[t] = 0; lh[t + 256] = 0;
    lcur[t] = 0; lcur[t + 256] = 0;
    __syncthreads();
    int start = blockIdx.x * SCAT_EDGES;
    int end = min(E, start + SCAT_EDGES);
    for (int e = start + t; e < end; e += 256)
        atomicAdd(&lh[dst[e] >> BSHIFT], 1);
    __syncthreads();
    for (int b = t; b < nbuck; b += 256)
        if (lh[b]) lbase[b] = atomicAdd(&gcur[b], lh[b]);
    __syncthreads();
    for (int e = start + t; e < end; e += 256) {
        int d = dst[e];
        int b = d >> BSHIFT;
        int slot = atomicAdd(&lcur[b], 1);
        pairs[lbase[b] + slot] = ((unsigned int)src[e] << BSHIFT) | (unsigned int)(d & (BUCKET - 1));
    }
}

__global__ __launch_bounds__(256) void build_kernel(const unsigned int* __restrict__ pairs,
                                                    const int* __restrict__ bbase,
                                                    int* __restrict__ rowptr,
                                                    int* __restrict__ col,
                                                    int n, int E) {
    __shared__ int ldeg[BUCKET];
    __shared__ int pre[BUCKET];
    __shared__ int cur[BUCKET];
    int t = threadIdx.x;
    int nbase = blockIdx.x << BSHIFT;
    int e0 = bbase[blockIdx.x], e1 = bbase[blockIdx.x + 1];
    ldeg[t] = 0; cur[t] = 0;
    __syncthreads();
    for (int e = e0 + t; e < e1; e += 256)
        atomicAdd(&ldeg[pairs[e] & (BUCKET - 1)], 1);
    __syncthreads();
    int v = ldeg[t];
    pre[t] = v;
    __syncthreads();
    for (int off = 1; off < 256; off <<= 1) {
        int u = (t >= off) ? pre[t - off] : 0;
        __syncthreads();
        pre[t] += u;
        __syncthreads();
    }
    int excl = pre[t] - v;
    __syncthreads();
    pre[t] = excl;
    __syncthreads();
    int node = nbase + t;
    if (node < n) rowptr[node] = e0 + excl;
    if (blockIdx.x == 0 && t == 0) rowptr[n] = E;
    for (int e = e0 + t; e < e1; e += 256) {
        unsigned int p = pairs[e];
        int l = (int)(p & (BUCKET - 1));
        int pos = atomicAdd(&cur[l], 1);
        col[e0 + pre[l] + pos] = (int)(p >> BSHIFT);
    }
}

// --- Dense transform v4: P[v]=in[v]@Wl (bf16), Q[v]=in[v]@Wr+bl (f32).
// Thread owns feature f, computes BOTH outputs.  Weight columns live in
// float2 wv[64] = 128 VGPRs (static indices only; launch_bounds(256,2) gives
// the 256-VGPR cap they need).  LDS: 128-row x-tile only.  Group g of 4
// handles 32 rows as 8 quads; quad loop NOT unrolled (small live range).
// In-place safe (in==Qh): block reads only its own rows, writes after sync.
__global__ __launch_bounds__(256, 2) void transform_kernel(
    const float* in, float* Qh, __hip_bfloat16* __restrict__ Pb,
    const float* __restrict__ Wl, const float* __restrict__ bl,
    const float* __restrict__ Wr, int n)
{
    __shared__ float4 tile[TROWS * 16];   // 32 KB
    int tid = threadIdx.x;
    int f = tid & 63, g = tid >> 6;

    float2 wv[64];
    #pragma unroll
    for (int k = 0; k < 64; ++k)
        wv[k] = make_float2(Wl[k * 64 + f], Wr[k * 64 + f]);
    float bias = bl[f];

    int base = blockIdx.x * TROWS;
    int nvalid = n - base; if (nvalid > TROWS) nvalid = TROWS;
    const float4* srcp = (const float4*)(in + (size_t)base * 64);
    for (int i = tid; i < nvalid * 16; i += 256) tile[i] = srcp[i];
    __syncthreads();

    #pragma unroll 1
    for (int s = 0; s < 8; ++s) {
        int r0 = (g << 5) + (s << 2);
        if (r0 >= nvalid) continue;
        float p0 = 0.f, p1 = 0.f, p2 = 0.f, p3 = 0.f;
        float q0 = bias, q1 = bias, q2 = bias, q3 = bias;
        #pragma unroll
        for (int kq = 0; kq < 16; ++kq) {
            float4 x0 = tile[(r0 + 0) * 16 + kq];
            float4 x1 = tile[(r0 + 1) * 16 + kq];
            float4 x2 = tile[(r0 + 2) * 16 + kq];
            float4 x3 = tile[(r0 + 3) * 16 + kq];
            #pragma unroll
            for (int j = 0; j < 4; ++j) {
                float2 ww = wv[4 * kq + j];
                float v0 = (&x0.x)[j], v1 = (&x1.x)[j];
                float v2 = (&x2.x)[j], v3 = (&x3.x)[j];
                p0 = fmaf(v0, ww.x, p0); q0 = fmaf(v0, ww.y, q0);
                p1 = fmaf(v1, ww.x, p1); q1 = fmaf(v1, ww.y, q1);
                p2 = fmaf(v2, ww.x, p2); q2 = fmaf(v2, ww.y, q2);
                p3 = fmaf(v3, ww.x, p3); q3 = fmaf(v3, ww.y, q3);
            }
        }
        int v = base + r0;
        if (v + 0 < n) { Pb[(size_t)(v + 0) * 64 + f] = __float2bfloat16(p0); Qh[(size_t)(v + 0) * 64 + f] = q0; }
        if (v + 1 < n) { Pb[(size_t)(v + 1) * 64 + f] = __float2bfloat16(p1); Qh[(size_t)(v + 1) * 64 + f] = q1; }
        if (v + 2 < n) { Pb[(size_t)(v + 2) * 64 + f] = __float2bfloat16(p2); Qh[(size_t)(v + 2) * 64 + f] = q2; }
        if (v + 3 < n) { Pb[(size_t)(v + 3) * 64 + f] = __float2bfloat16(p3); Qh[(size_t)(v + 3) * 64 + f] = q3; }
    }
}

// --- Pure-memory gather: h[v] = relu( mean_{s in N(v)} P[s] + Q[v] ) -> Qh[v].
__global__ __launch_bounds__(256) void gather_kernel(
    const __hip_bfloat16* __restrict__ Pb, float* __restrict__ Qh,
    const int* __restrict__ rowptr, const int* __restrict__ col, int n)
{
    int tid = threadIdx.x;
    int wid = tid >> 6, lane = tid & 63;
    int w = blockIdx.x * 4 + wid;
    int nw = gridDim.x * 4;
    for (int v = w; v < n; v += nw) {
        int s0 = rowptr[v], s1 = rowptr[v + 1];
        int deg = s1 - s0;
        float q = Qh[(size_t)v * 64 + lane];
        float acc = 0.f;
        for (int base = 0; base < deg; base += 64) {
            int rem = deg - base;
            int cnt = rem < 64 ? rem : 64;
            int ci = (lane < cnt) ? col[s0 + base + lane] : 0;
            int j = 0;
            for (; j + 8 <= cnt; j += 8) {
                int i0 = __shfl(ci, j + 0), i1 = __shfl(ci, j + 1);
                int i2 = __shfl(ci, j + 2), i3 = __shfl(ci, j + 3);
                int i4 = __shfl(ci, j + 4), i5 = __shfl(ci, j + 5);
                int i6 = __shfl(ci, j + 6), i7 = __shfl(ci, j + 7);
                float t0 = __bfloat162float(Pb[(size_t)i0 * 64 + lane]);
                float t1 = __bfloat162float(Pb[(size_t)i1 * 64 + lane]);
                float t2 = __bfloat162float(Pb[(size_t)i2 * 64 + lane]);
                float t3 = __bfloat162float(Pb[(size_t)i3 * 64 + lane]);
                float t4 = __bfloat162float(Pb[(size_t)i4 * 64 + lane]);
                float t5 = __bfloat162float(Pb[(size_t)i5 * 64 + lane]);
                float t6 = __bfloat162float(Pb[(size_t)i6 * 64 + lane]);
                float t7 = __bfloat162float(Pb[(size_t)i7 * 64 + lane]);
                acc += ((t0 + t1) + (t2 + t3)) + ((t4 + t5) + (t6 + t7));
            }
            for (; j + 4 <= cnt; j += 4) {
                int i0 = __shfl(ci, j + 0), i1 = __shfl(ci, j + 1);
                int i2 = __shfl(ci, j + 2), i3 = __shfl(ci, j + 3);
                float t0 = __bfloat162float(Pb[(size_t)i0 * 64 + lane]);
                float t1 = __bfloat162float(Pb[(size_t)i1 * 64 + lane]);
                float t2 = __bfloat162float(Pb[(size_t)i2 * 64 + lane]);
                float t3 = __bfloat162float(Pb[(size_t)i3 * 64 + lane]);
                acc += (t0 + t1) + (t2 + t3);
            }
            for (; j < cnt; ++j)
                acc += __bfloat162float(Pb[(size_t)__shfl(ci, j) * 64 + lane]);
        }
        float res = acc / fmaxf((float)deg, 1.0f) + q;
        Qh[(size_t)v * 64 + lane] = fmaxf(res, 0.f);
    }
}

// --- Classifier + log_softmax on h rows (stride 64). ---
__global__ __launch_bounds__(256) void cls_kernel(
    const float* __restrict__ h, const float* __restrict__ Wc,
    const float* __restrict__ bc, float* __restrict__ out, int n)
{
    __shared__ float sW[64 * 10];
    __shared__ float sb[16];
    __shared__ float srow[4][4][64];
    int tid = threadIdx.x;
    for (int i = tid; i < 640; i += 256) sW[i] = Wc[i];
    if (tid < 10) sb[tid] = bc[tid];
    __syncthreads();

    int wid = tid >> 6, lane = tid & 63;
    int grp = lane >> 4, l16 = lane & 15;
    int w = blockIdx.x * 4 + wid;
    int nw = gridDim.x * 4;
    int ngroups = (n + 3) >> 2;
    for (int g = w; g < ngroups; g += nw) {
        int v0 = g * 4;
        #pragma unroll
        for (int r = 0; r < 4; ++r) {
            int vv = v0 + r;
            if (vv < n) srow[wid][r][lane] = h[(size_t)vv * 64 + lane];
        }
        int v = v0 + grp;
        float z = -INFINITY;
        if (v < n && l16 < 10) {
            z = sb[l16];
            #pragma unroll
            for (int k = 0; k < 64; ++k)
                z += srow[wid][grp][k] * sW[k * 10 + l16];
        }
        float m = z;
        for (int off = 8; off > 0; off >>= 1)
            m = fmaxf(m, __shfl_xor(m, off, 16));
        float e = (l16 < 10 && v < n) ? expf(z - m) : 0.f;
        float ssum = e;
        for (int off = 8; off > 0; off >>= 1)
            ssum += __shfl_xor(ssum, off, 16);
        if (v < n && l16 < 10)
            out[(size_t)v * 10 + l16] = z - m - logf(ssum);
    }
}

extern "C" void kernel_launch(void* const* d_in, const int* in_sizes, int n_in,
                              void* d_out, int out_size, void* d_ws, size_t ws_size,
                              hipStream_t stream) {
    const float* x   = (const float*)d_in[0];
    const int*   ei  = (const int*)d_in[1];
    const float* Wl1 = (const float*)d_in[2];
    const float* bl1 = (const float*)d_in[3];
    const float* Wr1 = (const float*)d_in[4];
    const float* Wl2 = (const float*)d_in[5];
    const float* bl2 = (const float*)d_in[6];
    const float* Wr2 = (const float*)d_in[7];
    const float* Wl3 = (const float*)d_in[8];
    const float* bl3 = (const float*)d_in[9];
    const float* Wr3 = (const float*)d_in[10];
    const float* Wc  = (const float*)d_in[11];
    const float* bc  = (const float*)d_in[12];
    float* outp = (float*)d_out;

    int n = in_sizes[0] / 64;
    int E = in_sizes[1] / 2;
    const int* srcp = ei;
    const int* dstp = ei + E;
    int nbuck = (n + BUCKET - 1) >> BSHIFT;
    int SB = (E + SCAT_EDGES - 1) / SCAT_EDGES;
    int ntile = (n + TROWS - 1) / TROWS;

    char* ws = (char*)d_ws;
    size_t off = 0;
    auto alloc = [&](size_t bytes) -> void* {
        void* p = ws + off;
        off += bytes;
        off = (off + 255) & ~(size_t)255;
        return p;
    };
    int*   ghist  = (int*)alloc((size_t)MAXB * 4);
    int*   bbase  = (int*)alloc((size_t)(MAXB + 1) * 4);
    int*   gcur   = (int*)alloc((size_t)MAXB * 4);
    int*   rowptr = (int*)alloc((size_t)(n + 1) * 4);
    unsigned int* pairs = (unsigned int*)alloc((size_t)E * 4);
    int*   colv   = (int*)alloc((size_t)E * 4);
    __hip_bfloat16* Pb = (__hip_bfloat16*)alloc((size_t)n * 64 * 2);
    float* Qh     = (float*)alloc((size_t)n * 64 * 4);
    (void)ws_size; (void)n_in; (void)out_size;

    hipMemsetAsync(ghist, 0, (size_t)MAXB * 4, stream);

    hist_kernel<<<SB, 256, 0, stream>>>(dstp, ghist, E, nbuck);
    scanb_kernel<<<1, 512, 0, stream>>>(ghist, bbase, gcur, nbuck, E);
    scatter_kernel<<<SB, 256, 0, stream>>>(srcp, dstp, gcur, pairs, E, nbuck);
    build_kernel<<<nbuck, 256, 0, stream>>>(pairs, bbase, rowptr, colv, n, E);

    transform_kernel<<<ntile, 256, 0, stream>>>(x,  Qh, Pb, Wl1, bl1, Wr1, n);
    gather_kernel<<<2048, 256, 0, stream>>>(Pb, Qh, rowptr, colv, n);
    transform_kernel<<<ntile, 256, 0, stream>>>(Qh, Qh, Pb, Wl2, bl2, Wr2, n);
    gather_kernel<<<2048, 256, 0, stream>>>(Pb, Qh, rowptr, colv, n);
    transform_kernel<<<ntile, 256, 0, stream>>>(Qh, Qh, Pb, Wl3, bl3, Wr3, n);
    gather_kernel<<<2048, 256, 0, stream>>>(Pb, Qh, rowptr, colv, n);

    cls_kernel<<<1024, 256, 0, stream>>>(Qh, Wc, bc, outp, n);
}

// Round 12
// 439.904 us; speedup vs baseline: 2.0050x; 2.0050x over previous
//
#include <hip/hip_runtime.h>
#include <hip/hip_bf16.h>
#include <math.h>

// ---------------------------------------------------------------------------
// GraphSAGE 3-layer + classifier + log_softmax.  Round 12.
//  - transform v5: round-8 structure (thread owns one output column, weights
//    re-read from L1 — the compiler WILL NOT keep w[64] resident: r8 remat,
//    r9 hoist, r11 spill) but with 16 accumulators per thread so each weight
//    read feeds 16 FMAs instead of 4.  Only 4 weight scalars live at a time
//    -> nothing for the allocator to spill.  VGPR ~60, LDS 32 KB.
//  - CSR packed-pair bucket sort + bf16-P gather + cls unchanged (round 9).
// ---------------------------------------------------------------------------

#define BSHIFT 8
#define BUCKET 256
#define MAXB 512
#define SCAT_EDGES 8192
#define TROWS 128

__global__ __launch_bounds__(256) void hist_kernel(const int* __restrict__ dst,
                                                   int* __restrict__ ghist,
                                                   int E, int nbuck) {
    __shared__ int lh[MAXB];
    int t = threadIdx.x;
    lh[t] = 0; lh[t + 256] = 0;
    __syncthreads();
    int start = blockIdx.x * SCAT_EDGES;
    int end = min(E, start + SCAT_EDGES);
    for (int e = start + t; e < end; e += 256)
        atomicAdd(&lh[dst[e] >> BSHIFT], 1);
    __syncthreads();
    for (int b = t; b < nbuck; b += 256)
        if (lh[b]) atomicAdd(&ghist[b], lh[b]);
}

__global__ __launch_bounds__(512) void scanb_kernel(const int* __restrict__ ghist,
                                                    int* __restrict__ bbase,
                                                    int* __restrict__ gcur,
                                                    int nbuck, int E) {
    __shared__ int s[MAXB];
    int t = threadIdx.x;
    int v = (t < nbuck) ? ghist[t] : 0;
    s[t] = v;
    __syncthreads();
    for (int off = 1; off < MAXB; off <<= 1) {
        int u = (t >= off) ? s[t - off] : 0;
        __syncthreads();
        s[t] += u;
        __syncthreads();
    }
    int excl = s[t] - v;
    if (t < nbuck) { bbase[t] = excl; gcur[t] = excl; }
    if (t == 0) bbase[nbuck] = E;
}

__global__ __launch_bounds__(256) void scatter_kernel(const int* __restrict__ src,
                                                      const int* __restrict__ dst,
                                                      int* __restrict__ gcur,
                                                      unsigned int* __restrict__ pairs,
                                                      int E, int nbuck) {
    __shared__ int lh[MAXB];
    __shared__ int lbase[MAXB];
    __shared__ int lcur[MAXB];
    int t = threadIdx.x;
    lh[t] = 0; lh[t + 256] = 0;
    lcur[t] = 0; lcur[t + 256] = 0;
    __syncthreads();
    int start = blockIdx.x * SCAT_EDGES;
    int end = min(E, start + SCAT_EDGES);
    for (int e = start + t; e < end; e += 256)
        atomicAdd(&lh[dst[e] >> BSHIFT], 1);
    __syncthreads();
    for (int b = t; b < nbuck; b += 256)
        if (lh[b]) lbase[b] = atomicAdd(&gcur[b], lh[b]);
    __syncthreads();
    for (int e = start + t; e < end; e += 256) {
        int d = dst[e];
        int b = d >> BSHIFT;
        int slot = atomicAdd(&lcur[b], 1);
        pairs[lbase[b] + slot] = ((unsigned int)src[e] << BSHIFT) | (unsigned int)(d & (BUCKET - 1));
    }
}

__global__ __launch_bounds__(256) void build_kernel(const unsigned int* __restrict__ pairs,
                                                    const int* __restrict__ bbase,
                                                    int* __restrict__ rowptr,
                                                    int* __restrict__ col,
                                                    int n, int E) {
    __shared__ int ldeg[BUCKET];
    __shared__ int pre[BUCKET];
    __shared__ int cur[BUCKET];
    int t = threadIdx.x;
    int nbase = blockIdx.x << BSHIFT;
    int e0 = bbase[blockIdx.x], e1 = bbase[blockIdx.x + 1];
    ldeg[t] = 0; cur[t] = 0;
    __syncthreads();
    for (int e = e0 + t; e < e1; e += 256)
        atomicAdd(&ldeg[pairs[e] & (BUCKET - 1)], 1);
    __syncthreads();
    int v = ldeg[t];
    pre[t] = v;
    __syncthreads();
    for (int off = 1; off < 256; off <<= 1) {
        int u = (t >= off) ? pre[t - off] : 0;
        __syncthreads();
        pre[t] += u;
        __syncthreads();
    }
    int excl = pre[t] - v;
    __syncthreads();
    pre[t] = excl;
    __syncthreads();
    int node = nbase + t;
    if (node < n) rowptr[node] = e0 + excl;
    if (blockIdx.x == 0 && t == 0) rowptr[n] = E;
    for (int e = e0 + t; e < e1; e += 256) {
        unsigned int p = pairs[e];
        int l = (int)(p & (BUCKET - 1));
        int pos = atomicAdd(&cur[l], 1);
        col[e0 + pre[l] + pos] = (int)(p >> BSHIFT);
    }
}

// --- Dense transform v5: P[v]=in[v]@Wl (bf16), Q[v]=in[v]@Wr+bl (f32).
// Thread owns one output column c (c<64: P col f via Wl; c>=64: Q col f via
// Wr).  16 accumulators (static indices); weights re-read 4 scalars at a
// time inside the kq loop (short live range -> no spill/remat pressure);
// 128-row x-tile in LDS, all tile reads wave-uniform broadcasts.
// In-place safe (in==Qh): block reads its rows before the barrier, writes
// the same rows after; blocks disjoint.
__global__ __launch_bounds__(256, 4) void transform_kernel(
    const float* in, float* Qh, __hip_bfloat16* __restrict__ Pb,
    const float* __restrict__ Wl, const float* __restrict__ bl,
    const float* __restrict__ Wr, int n)
{
    __shared__ float4 tile[TROWS * 16];   // 32 KB
    int tid = threadIdx.x;
    int c = tid & 127;
    int grp = tid >> 7;                   // 0/1 -> rows [0,64) / [64,128)
    bool isQ = (c >= 64);
    int f = c & 63;
    const float* W = isQ ? Wr : Wl;
    float bias = isQ ? bl[f] : 0.f;

    int base = blockIdx.x * TROWS;
    int nvalid = n - base; if (nvalid > TROWS) nvalid = TROWS;
    const float4* srcp = (const float4*)(in + (size_t)base * 64);
    for (int i = tid; i < nvalid * 16; i += 256) tile[i] = srcp[i];
    __syncthreads();

    #pragma unroll 1
    for (int s = 0; s < 4; ++s) {
        int r0 = (grp << 6) + (s << 4);   // 16 rows per step
        if (r0 >= nvalid) continue;
        float a[16];
        #pragma unroll
        for (int i = 0; i < 16; ++i) a[i] = bias;
        #pragma unroll 1
        for (int kq = 0; kq < 16; ++kq) {
            float w0 = W[(4 * kq + 0) * 64 + f];
            float w1 = W[(4 * kq + 1) * 64 + f];
            float w2 = W[(4 * kq + 2) * 64 + f];
            float w3 = W[(4 * kq + 3) * 64 + f];
            #pragma unroll
            for (int rc = 0; rc < 4; ++rc) {
                float4 x0 = tile[(r0 + rc * 4 + 0) * 16 + kq];
                float4 x1 = tile[(r0 + rc * 4 + 1) * 16 + kq];
                float4 x2 = tile[(r0 + rc * 4 + 2) * 16 + kq];
                float4 x3 = tile[(r0 + rc * 4 + 3) * 16 + kq];
                a[rc * 4 + 0] = fmaf(x0.w, w3, fmaf(x0.z, w2, fmaf(x0.y, w1, fmaf(x0.x, w0, a[rc * 4 + 0]))));
                a[rc * 4 + 1] = fmaf(x1.w, w3, fmaf(x1.z, w2, fmaf(x1.y, w1, fmaf(x1.x, w0, a[rc * 4 + 1]))));
                a[rc * 4 + 2] = fmaf(x2.w, w3, fmaf(x2.z, w2, fmaf(x2.y, w1, fmaf(x2.x, w0, a[rc * 4 + 2]))));
                a[rc * 4 + 3] = fmaf(x3.w, w3, fmaf(x3.z, w2, fmaf(x3.y, w1, fmaf(x3.x, w0, a[rc * 4 + 3]))));
            }
        }
        #pragma unroll
        for (int i = 0; i < 16; ++i) {
            int v = base + r0 + i;
            if (v < n) {
                if (isQ) Qh[(size_t)v * 64 + f] = a[i];
                else     Pb[(size_t)v * 64 + f] = __float2bfloat16(a[i]);
            }
        }
    }
}

// --- Pure-memory gather: h[v] = relu( mean_{s in N(v)} P[s] + Q[v] ) -> Qh[v].
__global__ __launch_bounds__(256) void gather_kernel(
    const __hip_bfloat16* __restrict__ Pb, float* __restrict__ Qh,
    const int* __restrict__ rowptr, const int* __restrict__ col, int n)
{
    int tid = threadIdx.x;
    int wid = tid >> 6, lane = tid & 63;
    int w = blockIdx.x * 4 + wid;
    int nw = gridDim.x * 4;
    for (int v = w; v < n; v += nw) {
        int s0 = rowptr[v], s1 = rowptr[v + 1];
        int deg = s1 - s0;
        float q = Qh[(size_t)v * 64 + lane];
        float acc = 0.f;
        for (int base = 0; base < deg; base += 64) {
            int rem = deg - base;
            int cnt = rem < 64 ? rem : 64;
            int ci = (lane < cnt) ? col[s0 + base + lane] : 0;
            int j = 0;
            for (; j + 8 <= cnt; j += 8) {
                int i0 = __shfl(ci, j + 0), i1 = __shfl(ci, j + 1);
                int i2 = __shfl(ci, j + 2), i3 = __shfl(ci, j + 3);
                int i4 = __shfl(ci, j + 4), i5 = __shfl(ci, j + 5);
                int i6 = __shfl(ci, j + 6), i7 = __shfl(ci, j + 7);
                float t0 = __bfloat162float(Pb[(size_t)i0 * 64 + lane]);
                float t1 = __bfloat162float(Pb[(size_t)i1 * 64 + lane]);
                float t2 = __bfloat162float(Pb[(size_t)i2 * 64 + lane]);
                float t3 = __bfloat162float(Pb[(size_t)i3 * 64 + lane]);
                float t4 = __bfloat162float(Pb[(size_t)i4 * 64 + lane]);
                float t5 = __bfloat162float(Pb[(size_t)i5 * 64 + lane]);
                float t6 = __bfloat162float(Pb[(size_t)i6 * 64 + lane]);
                float t7 = __bfloat162float(Pb[(size_t)i7 * 64 + lane]);
                acc += ((t0 + t1) + (t2 + t3)) + ((t4 + t5) + (t6 + t7));
            }
            for (; j + 4 <= cnt; j += 4) {
                int i0 = __shfl(ci, j + 0), i1 = __shfl(ci, j + 1);
                int i2 = __shfl(ci, j + 2), i3 = __shfl(ci, j + 3);
                float t0 = __bfloat162float(Pb[(size_t)i0 * 64 + lane]);
                float t1 = __bfloat162float(Pb[(size_t)i1 * 64 + lane]);
                float t2 = __bfloat162float(Pb[(size_t)i2 * 64 + lane]);
                float t3 = __bfloat162float(Pb[(size_t)i3 * 64 + lane]);
                acc += (t0 + t1) + (t2 + t3);
            }
            for (; j < cnt; ++j)
                acc += __bfloat162float(Pb[(size_t)__shfl(ci, j) * 64 + lane]);
        }
        float res = acc / fmaxf((float)deg, 1.0f) + q;
        Qh[(size_t)v * 64 + lane] = fmaxf(res, 0.f);
    }
}

// --- Classifier + log_softmax on h rows (stride 64). ---
__global__ __launch_bounds__(256) void cls_kernel(
    const float* __restrict__ h, const float* __restrict__ Wc,
    const float* __restrict__ bc, float* __restrict__ out, int n)
{
    __shared__ float sW[64 * 10];
    __shared__ float sb[16];
    __shared__ float srow[4][4][64];
    int tid = threadIdx.x;
    for (int i = tid; i < 640; i += 256) sW[i] = Wc[i];
    if (tid < 10) sb[tid] = bc[tid];
    __syncthreads();

    int wid = tid >> 6, lane = tid & 63;
    int grp = lane >> 4, l16 = lane & 15;
    int w = blockIdx.x * 4 + wid;
    int nw = gridDim.x * 4;
    int ngroups = (n + 3) >> 2;
    for (int g = w; g < ngroups; g += nw) {
        int v0 = g * 4;
        #pragma unroll
        for (int r = 0; r < 4; ++r) {
            int vv = v0 + r;
            if (vv < n) srow[wid][r][lane] = h[(size_t)vv * 64 + lane];
        }
        int v = v0 + grp;
        float z = -INFINITY;
        if (v < n && l16 < 10) {
            z = sb[l16];
            #pragma unroll
            for (int k = 0; k < 64; ++k)
                z += srow[wid][grp][k] * sW[k * 10 + l16];
        }
        float m = z;
        for (int off = 8; off > 0; off >>= 1)
            m = fmaxf(m, __shfl_xor(m, off, 16));
        float e = (l16 < 10 && v < n) ? expf(z - m) : 0.f;
        float ssum = e;
        for (int off = 8; off > 0; off >>= 1)
            ssum += __shfl_xor(ssum, off, 16);
        if (v < n && l16 < 10)
            out[(size_t)v * 10 + l16] = z - m - logf(ssum);
    }
}

extern "C" void kernel_launch(void* const* d_in, const int* in_sizes, int n_in,
                              void* d_out, int out_size, void* d_ws, size_t ws_size,
                              hipStream_t stream) {
    const float* x   = (const float*)d_in[0];
    const int*   ei  = (const int*)d_in[1];
    const float* Wl1 = (const float*)d_in[2];
    const float* bl1 = (const float*)d_in[3];
    const float* Wr1 = (const float*)d_in[4];
    const float* Wl2 = (const float*)d_in[5];
    const float* bl2 = (const float*)d_in[6];
    const float* Wr2 = (const float*)d_in[7];
    const float* Wl3 = (const float*)d_in[8];
    const float* bl3 = (const float*)d_in[9];
    const float* Wr3 = (const float*)d_in[10];
    const float* Wc  = (const float*)d_in[11];
    const float* bc  = (const float*)d_in[12];
    float* outp = (float*)d_out;

    int n = in_sizes[0] / 64;
    int E = in_sizes[1] / 2;
    const int* srcp = ei;
    const int* dstp = ei + E;
    int nbuck = (n + BUCKET - 1) >> BSHIFT;
    int SB = (E + SCAT_EDGES - 1) / SCAT_EDGES;
    int ntile = (n + TROWS - 1) / TROWS;

    char* ws = (char*)d_ws;
    size_t off = 0;
    auto alloc = [&](size_t bytes) -> void* {
        void* p = ws + off;
        off += bytes;
        off = (off + 255) & ~(size_t)255;
        return p;
    };
    int*   ghist  = (int*)alloc((size_t)MAXB * 4);
    int*   bbase  = (int*)alloc((size_t)(MAXB + 1) * 4);
    int*   gcur   = (int*)alloc((size_t)MAXB * 4);
    int*   rowptr = (int*)alloc((size_t)(n + 1) * 4);
    unsigned int* pairs = (unsigned int*)alloc((size_t)E * 4);
    int*   colv   = (int*)alloc((size_t)E * 4);
    __hip_bfloat16* Pb = (__hip_bfloat16*)alloc((size_t)n * 64 * 2);
    float* Qh     = (float*)alloc((size_t)n * 64 * 4);
    (void)ws_size; (void)n_in; (void)out_size;

    hipMemsetAsync(ghist, 0, (size_t)MAXB * 4, stream);

    hist_kernel<<<SB, 256, 0, stream>>>(dstp, ghist, E, nbuck);
    scanb_kernel<<<1, 512, 0, stream>>>(ghist, bbase, gcur, nbuck, E);
    scatter_kernel<<<SB, 256, 0, stream>>>(srcp, dstp, gcur, pairs, E, nbuck);
    build_kernel<<<nbuck, 256, 0, stream>>>(pairs, bbase, rowptr, colv, n, E);

    transform_kernel<<<ntile, 256, 0, stream>>>(x,  Qh, Pb, Wl1, bl1, Wr1, n);
    gather_kernel<<<2048, 256, 0, stream>>>(Pb, Qh, rowptr, colv, n);
    transform_kernel<<<ntile, 256, 0, stream>>>(Qh, Qh, Pb, Wl2, bl2, Wr2, n);
    gather_kernel<<<2048, 256, 0, stream>>>(Pb, Qh, rowptr, colv, n);
    transform_kernel<<<ntile, 256, 0, stream>>>(Qh, Qh, Pb, Wl3, bl3, Wr3, n);
    gather_kernel<<<2048, 256, 0, stream>>>(Pb, Qh, rowptr, colv, n);

    cls_kernel<<<1024, 256, 0, stream>>>(Qh, Wc, bc, outp, n);
}

// Round 15
// 384.289 us; speedup vs baseline: 2.2951x; 1.1447x over previous
//
#include <hip/hip_runtime.h>
#include <hip/hip_bf16.h>
#include <math.h>

// ---------------------------------------------------------------------------
// GraphSAGE 3-layer + classifier + log_softmax.  Round 15 (r13 + compile fix:
// __hip_bfloat16 has no .data member on this ROCm -> pack via union of
// __hip_bfloat16[4]/ushort4 with __float2bfloat16).
//  - transform v6: 4x4 micro-tile GEMM.  Thread owns 4 cols x 16 rows
//    (64 static accumulators).  Per LDS float4 row-read: 16 FMAs (1 B/FMA,
//    4x less LDS traffic than v5 whose 1024 b128/thread = measured 58us
//    LDS-pipe bound).  Weights: 4 float4/kq from L1, 16 scalars live ->
//    no spill (r11 lesson).  P written as packed ushort4.
//  - CSR packed-pair bucket sort + bf16-P gather + cls unchanged.
// ---------------------------------------------------------------------------

#define BSHIFT 8
#define BUCKET 256
#define MAXB 512
#define SCAT_EDGES 8192
#define TROWS 128

__global__ __launch_bounds__(256) void hist_kernel(const int* __restrict__ dst,
                                                   int* __restrict__ ghist,
                                                   int E, int nbuck) {
    __shared__ int lh[MAXB];
    int t = threadIdx.x;
    lh[t] = 0; lh[t + 256] = 0;
    __syncthreads();
    int start = blockIdx.x * SCAT_EDGES;
    int end = min(E, start + SCAT_EDGES);
    for (int e = start + t; e < end; e += 256)
        atomicAdd(&lh[dst[e] >> BSHIFT], 1);
    __syncthreads();
    for (int b = t; b < nbuck; b += 256)
        if (lh[b]) atomicAdd(&ghist[b], lh[b]);
}

__global__ __launch_bounds__(512) void scanb_kernel(const int* __restrict__ ghist,
                                                    int* __restrict__ bbase,
                                                    int* __restrict__ gcur,
                                                    int nbuck, int E) {
    __shared__ int s[MAXB];
    int t = threadIdx.x;
    int v = (t < nbuck) ? ghist[t] : 0;
    s[t] = v;
    __syncthreads();
    for (int off = 1; off < MAXB; off <<= 1) {
        int u = (t >= off) ? s[t - off] : 0;
        __syncthreads();
        s[t] += u;
        __syncthreads();
    }
    int excl = s[t] - v;
    if (t < nbuck) { bbase[t] = excl; gcur[t] = excl; }
    if (t == 0) bbase[nbuck] = E;
}

__global__ __launch_bounds__(256) void scatter_kernel(const int* __restrict__ src,
                                                      const int* __restrict__ dst,
                                                      int* __restrict__ gcur,
                                                      unsigned int* __restrict__ pairs,
                                                      int E, int nbuck) {
    __shared__ int lh[MAXB];
    __shared__ int lbase[MAXB];
    __shared__ int lcur[MAXB];
    int t = threadIdx.x;
    lh[t] = 0; lh[t + 256] = 0;
    lcur[t] = 0; lcur[t + 256] = 0;
    __syncthreads();
    int start = blockIdx.x * SCAT_EDGES;
    int end = min(E, start + SCAT_EDGES);
    for (int e = start + t; e < end; e += 256)
        atomicAdd(&lh[dst[e] >> BSHIFT], 1);
    __syncthreads();
    for (int b = t; b < nbuck; b += 256)
        if (lh[b]) lbase[b] = atomicAdd(&gcur[b], lh[b]);
    __syncthreads();
    for (int e = start + t; e < end; e += 256) {
        int d = dst[e];
        int b = d >> BSHIFT;
        int slot = atomicAdd(&lcur[b], 1);
        pairs[lbase[b] + slot] = ((unsigned int)src[e] << BSHIFT) | (unsigned int)(d & (BUCKET - 1));
    }
}

__global__ __launch_bounds__(256) void build_kernel(const unsigned int* __restrict__ pairs,
                                                    const int* __restrict__ bbase,
                                                    int* __restrict__ rowptr,
                                                    int* __restrict__ col,
                                                    int n, int E) {
    __shared__ int ldeg[BUCKET];
    __shared__ int pre[BUCKET];
    __shared__ int cur[BUCKET];
    int t = threadIdx.x;
    int nbase = blockIdx.x << BSHIFT;
    int e0 = bbase[blockIdx.x], e1 = bbase[blockIdx.x + 1];
    ldeg[t] = 0; cur[t] = 0;
    __syncthreads();
    for (int e = e0 + t; e < e1; e += 256)
        atomicAdd(&ldeg[pairs[e] & (BUCKET - 1)], 1);
    __syncthreads();
    int v = ldeg[t];
    pre[t] = v;
    __syncthreads();
    for (int off = 1; off < 256; off <<= 1) {
        int u = (t >= off) ? pre[t - off] : 0;
        __syncthreads();
        pre[t] += u;
        __syncthreads();
    }
    int excl = pre[t] - v;
    __syncthreads();
    pre[t] = excl;
    __syncthreads();
    int node = nbase + t;
    if (node < n) rowptr[node] = e0 + excl;
    if (blockIdx.x == 0 && t == 0) rowptr[n] = E;
    for (int e = e0 + t; e < e1; e += 256) {
        unsigned int p = pairs[e];
        int l = (int)(p & (BUCKET - 1));
        int pos = atomicAdd(&cur[l], 1);
        col[e0 + pre[l] + pos] = (int)(p >> BSHIFT);
    }
}

// --- Dense transform v6: P[v]=in[v]@Wl (bf16), Q[v]=in[v]@Wr+bl (f32).
// 4x4 micro-tile: thread (tc,tr) owns cols 4*(tc&15)..+3 of P (tc<16) or Q
// (tc>=16), and 16 rows {tr*4 + s*32 + rr}.  64 static accumulators.
// Per kq: 4 weight float4 (L1, coalesced) + 16 row float4 (LDS broadcast)
// -> 256 FMA.  In-place safe (in==Qh): block reads its own rows before the
// barrier, writes them after; blocks disjoint.
__global__ __launch_bounds__(256, 3) void transform_kernel(
    const float* in, float* Qh, __hip_bfloat16* __restrict__ Pb,
    const float* __restrict__ Wl, const float* __restrict__ bl,
    const float* __restrict__ Wr, int n)
{
    __shared__ float4 tile[TROWS * 16];   // 32 KB
    int tid = threadIdx.x;
    int tc = tid & 31;                    // col-quad
    int tr = tid >> 5;                    // row group 0..7
    bool isQ = (tc >= 16);
    int f4 = (tc & 15) * 4;
    const float* W = isQ ? Wr : Wl;

    int base = blockIdx.x * TROWS;
    int nvalid = n - base; if (nvalid > TROWS) nvalid = TROWS;
    const float4* srcp = (const float4*)(in + (size_t)base * 64);
    for (int i = tid; i < nvalid * 16; i += 256) tile[i] = srcp[i];

    float b0 = 0.f, b1 = 0.f, b2 = 0.f, b3 = 0.f;
    if (isQ) { b0 = bl[f4]; b1 = bl[f4 + 1]; b2 = bl[f4 + 2]; b3 = bl[f4 + 3]; }
    __syncthreads();

    float a[16][4];
    #pragma unroll
    for (int r = 0; r < 16; ++r) { a[r][0] = b0; a[r][1] = b1; a[r][2] = b2; a[r][3] = b3; }

    #pragma unroll 1
    for (int kq = 0; kq < 16; ++kq) {
        float4 w0 = *(const float4*)(W + (4 * kq + 0) * 64 + f4);
        float4 w1 = *(const float4*)(W + (4 * kq + 1) * 64 + f4);
        float4 w2 = *(const float4*)(W + (4 * kq + 2) * 64 + f4);
        float4 w3 = *(const float4*)(W + (4 * kq + 3) * 64 + f4);
        #pragma unroll
        for (int s = 0; s < 4; ++s) {
            #pragma unroll
            for (int rr = 0; rr < 4; ++rr) {
                int row = tr * 4 + s * 32 + rr;
                float4 x = tile[row * 16 + kq];
                int ai = s * 4 + rr;
                a[ai][0] = fmaf(x.x, w0.x, a[ai][0]); a[ai][1] = fmaf(x.x, w0.y, a[ai][1]);
                a[ai][2] = fmaf(x.x, w0.z, a[ai][2]); a[ai][3] = fmaf(x.x, w0.w, a[ai][3]);
                a[ai][0] = fmaf(x.y, w1.x, a[ai][0]); a[ai][1] = fmaf(x.y, w1.y, a[ai][1]);
                a[ai][2] = fmaf(x.y, w1.z, a[ai][2]); a[ai][3] = fmaf(x.y, w1.w, a[ai][3]);
                a[ai][0] = fmaf(x.z, w2.x, a[ai][0]); a[ai][1] = fmaf(x.z, w2.y, a[ai][1]);
                a[ai][2] = fmaf(x.z, w2.z, a[ai][2]); a[ai][3] = fmaf(x.z, w2.w, a[ai][3]);
                a[ai][0] = fmaf(x.w, w3.x, a[ai][0]); a[ai][1] = fmaf(x.w, w3.y, a[ai][1]);
                a[ai][2] = fmaf(x.w, w3.z, a[ai][2]); a[ai][3] = fmaf(x.w, w3.w, a[ai][3]);
            }
        }
    }

    #pragma unroll
    for (int s = 0; s < 4; ++s) {
        #pragma unroll
        for (int rr = 0; rr < 4; ++rr) {
            int row = tr * 4 + s * 32 + rr;
            int v = base + row;
            if (v >= n) continue;
            int ai = s * 4 + rr;
            if (isQ) {
                *(float4*)(Qh + (size_t)v * 64 + f4) =
                    make_float4(a[ai][0], a[ai][1], a[ai][2], a[ai][3]);
            } else {
                union { ushort4 u4; __hip_bfloat16 b[4]; } pk;
                pk.b[0] = __float2bfloat16(a[ai][0]);
                pk.b[1] = __float2bfloat16(a[ai][1]);
                pk.b[2] = __float2bfloat16(a[ai][2]);
                pk.b[3] = __float2bfloat16(a[ai][3]);
                *(ushort4*)((unsigned short*)Pb + (size_t)v * 64 + f4) = pk.u4;
            }
        }
    }
}

// --- Pure-memory gather: h[v] = relu( mean_{s in N(v)} P[s] + Q[v] ) -> Qh[v].
__global__ __launch_bounds__(256) void gather_kernel(
    const __hip_bfloat16* __restrict__ Pb, float* __restrict__ Qh,
    const int* __restrict__ rowptr, const int* __restrict__ col, int n)
{
    int tid = threadIdx.x;
    int wid = tid >> 6, lane = tid & 63;
    int w = blockIdx.x * 4 + wid;
    int nw = gridDim.x * 4;
    for (int v = w; v < n; v += nw) {
        int s0 = rowptr[v], s1 = rowptr[v + 1];
        int deg = s1 - s0;
        float q = Qh[(size_t)v * 64 + lane];
        float acc = 0.f;
        for (int base = 0; base < deg; base += 64) {
            int rem = deg - base;
            int cnt = rem < 64 ? rem : 64;
            int ci = (lane < cnt) ? col[s0 + base + lane] : 0;
            int j = 0;
            for (; j + 8 <= cnt; j += 8) {
                int i0 = __shfl(ci, j + 0), i1 = __shfl(ci, j + 1);
                int i2 = __shfl(ci, j + 2), i3 = __shfl(ci, j + 3);
                int i4 = __shfl(ci, j + 4), i5 = __shfl(ci, j + 5);
                int i6 = __shfl(ci, j + 6), i7 = __shfl(ci, j + 7);
                float t0 = __bfloat162float(Pb[(size_t)i0 * 64 + lane]);
                float t1 = __bfloat162float(Pb[(size_t)i1 * 64 + lane]);
                float t2 = __bfloat162float(Pb[(size_t)i2 * 64 + lane]);
                float t3 = __bfloat162float(Pb[(size_t)i3 * 64 + lane]);
                float t4 = __bfloat162float(Pb[(size_t)i4 * 64 + lane]);
                float t5 = __bfloat162float(Pb[(size_t)i5 * 64 + lane]);
                float t6 = __bfloat162float(Pb[(size_t)i6 * 64 + lane]);
                float t7 = __bfloat162float(Pb[(size_t)i7 * 64 + lane]);
                acc += ((t0 + t1) + (t2 + t3)) + ((t4 + t5) + (t6 + t7));
            }
            for (; j + 4 <= cnt; j += 4) {
                int i0 = __shfl(ci, j + 0), i1 = __shfl(ci, j + 1);
                int i2 = __shfl(ci, j + 2), i3 = __shfl(ci, j + 3);
                float t0 = __bfloat162float(Pb[(size_t)i0 * 64 + lane]);
                float t1 = __bfloat162float(Pb[(size_t)i1 * 64 + lane]);
                float t2 = __bfloat162float(Pb[(size_t)i2 * 64 + lane]);
                float t3 = __bfloat162float(Pb[(size_t)i3 * 64 + lane]);
                acc += (t0 + t1) + (t2 + t3);
            }
            for (; j < cnt; ++j)
                acc += __bfloat162float(Pb[(size_t)__shfl(ci, j) * 64 + lane]);
        }
        float res = acc / fmaxf((float)deg, 1.0f) + q;
        Qh[(size_t)v * 64 + lane] = fmaxf(res, 0.f);
    }
}

// --- Classifier + log_softmax on h rows (stride 64). ---
__global__ __launch_bounds__(256) void cls_kernel(
    const float* __restrict__ h, const float* __restrict__ Wc,
    const float* __restrict__ bc, float* __restrict__ out, int n)
{
    __shared__ float sW[64 * 10];
    __shared__ float sb[16];
    __shared__ float srow[4][4][64];
    int tid = threadIdx.x;
    for (int i = tid; i < 640; i += 256) sW[i] = Wc[i];
    if (tid < 10) sb[tid] = bc[tid];
    __syncthreads();

    int wid = tid >> 6, lane = tid & 63;
    int grp = lane >> 4, l16 = lane & 15;
    int w = blockIdx.x * 4 + wid;
    int nw = gridDim.x * 4;
    int ngroups = (n + 3) >> 2;
    for (int g = w; g < ngroups; g += nw) {
        int v0 = g * 4;
        #pragma unroll
        for (int r = 0; r < 4; ++r) {
            int vv = v0 + r;
            if (vv < n) srow[wid][r][lane] = h[(size_t)vv * 64 + lane];
        }
        int v = v0 + grp;
        float z = -INFINITY;
        if (v < n && l16 < 10) {
            z = sb[l16];
            #pragma unroll
            for (int k = 0; k < 64; ++k)
                z += srow[wid][grp][k] * sW[k * 10 + l16];
        }
        float m = z;
        for (int off = 8; off > 0; off >>= 1)
            m = fmaxf(m, __shfl_xor(m, off, 16));
        float e = (l16 < 10 && v < n) ? expf(z - m) : 0.f;
        float ssum = e;
        for (int off = 8; off > 0; off >>= 1)
            ssum += __shfl_xor(ssum, off, 16);
        if (v < n && l16 < 10)
            out[(size_t)v * 10 + l16] = z - m - logf(ssum);
    }
}

extern "C" void kernel_launch(void* const* d_in, const int* in_sizes, int n_in,
                              void* d_out, int out_size, void* d_ws, size_t ws_size,
                              hipStream_t stream) {
    const float* x   = (const float*)d_in[0];
    const int*   ei  = (const int*)d_in[1];
    const float* Wl1 = (const float*)d_in[2];
    const float* bl1 = (const float*)d_in[3];
    const float* Wr1 = (const float*)d_in[4];
    const float* Wl2 = (const float*)d_in[5];
    const float* bl2 = (const float*)d_in[6];
    const float* Wr2 = (const float*)d_in[7];
    const float* Wl3 = (const float*)d_in[8];
    const float* bl3 = (const float*)d_in[9];
    const float* Wr3 = (const float*)d_in[10];
    const float* Wc  = (const float*)d_in[11];
    const float* bc  = (const float*)d_in[12];
    float* outp = (float*)d_out;

    int n = in_sizes[0] / 64;
    int E = in_sizes[1] / 2;
    const int* srcp = ei;
    const int* dstp = ei + E;
    int nbuck = (n + BUCKET - 1) >> BSHIFT;
    int SB = (E + SCAT_EDGES - 1) / SCAT_EDGES;
    int ntile = (n + TROWS - 1) / TROWS;

    char* ws = (char*)d_ws;
    size_t off = 0;
    auto alloc = [&](size_t bytes) -> void* {
        void* p = ws + off;
        off += bytes;
        off = (off + 255) & ~(size_t)255;
        return p;
    };
    int*   ghist  = (int*)alloc((size_t)MAXB * 4);
    int*   bbase  = (int*)alloc((size_t)(MAXB + 1) * 4);
    int*   gcur   = (int*)alloc((size_t)MAXB * 4);
    int*   rowptr = (int*)alloc((size_t)(n + 1) * 4);
    unsigned int* pairs = (unsigned int*)alloc((size_t)E * 4);
    int*   colv   = (int*)alloc((size_t)E * 4);
    __hip_bfloat16* Pb = (__hip_bfloat16*)alloc((size_t)n * 64 * 2);
    float* Qh     = (float*)alloc((size_t)n * 64 * 4);
    (void)ws_size; (void)n_in; (void)out_size;

    hipMemsetAsync(ghist, 0, (size_t)MAXB * 4, stream);

    hist_kernel<<<SB, 256, 0, stream>>>(dstp, ghist, E, nbuck);
    scanb_kernel<<<1, 512, 0, stream>>>(ghist, bbase, gcur, nbuck, E);
    scatter_kernel<<<SB, 256, 0, stream>>>(srcp, dstp, gcur, pairs, E, nbuck);
    build_kernel<<<nbuck, 256, 0, stream>>>(pairs, bbase, rowptr, colv, n, E);

    transform_kernel<<<ntile, 256, 0, stream>>>(x,  Qh, Pb, Wl1, bl1, Wr1, n);
    gather_kernel<<<2048, 256, 0, stream>>>(Pb, Qh, rowptr, colv, n);
    transform_kernel<<<ntile, 256, 0, stream>>>(Qh, Qh, Pb, Wl2, bl2, Wr2, n);
    gather_kernel<<<2048, 256, 0, stream>>>(Pb, Qh, rowptr, colv, n);
    transform_kernel<<<ntile, 256, 0, stream>>>(Qh, Qh, Pb, Wl3, bl3, Wr3, n);
    gather_kernel<<<2048, 256, 0, stream>>>(Pb, Qh, rowptr, colv, n);

    cls_kernel<<<1024, 256, 0, stream>>>(Qh, Wc, bc, outp, n);
}